// Round 1
// baseline (98.237 us; speedup 1.0000x reference)
//
#include <hip/hip_runtime.h>
#include <math.h>

// N=1024, X_DIM=HID=Y_DIM=256.
// This round: 3 kernels -> 2. K0 = prep (weight pre-split to bf16 hi/lo,
// moment partials, zero out). KF = fully fused pipeline: 64 blocks x 512
// threads, each block owns 16 rows end-to-end; h stays in LDS (never global);
// w1/w2 streamed through a double-buffered LDS tile with reg prefetch
// (issue-early/write-late); CLUB epilogue + relu + one atomicAdd per block.
// Rules kept: no cross-block fences/spins (R4/R9); fire-and-forget atomics OK
// (R10). Numerics: identical Dekker 3-MFMA scheme, same K order as before.
constexpr int LSB = 72;  // bf16 LDS row stride for 64-k tiles (144 B) — benign banks

typedef short bf16x8 __attribute__((ext_vector_type(8)));
typedef float f32x4  __attribute__((ext_vector_type(4)));

__device__ __forceinline__ unsigned short f2bf_rne(float f) {
    unsigned u = __float_as_uint(f);
    unsigned r = (u + 0x7fff + ((u >> 16) & 1)) >> 16;
    return (unsigned short)r;
}
__device__ __forceinline__ float bf2f(unsigned short h) {
    return __uint_as_float(((unsigned)h) << 16);
}
__device__ __forceinline__ void split4(float4 v, ushort4& hi, ushort4& lo) {
    hi.x = f2bf_rne(v.x); lo.x = f2bf_rne(v.x - bf2f(hi.x));
    hi.y = f2bf_rne(v.y); lo.y = f2bf_rne(v.y - bf2f(hi.y));
    hi.z = f2bf_rne(v.z); lo.z = f2bf_rne(v.z - bf2f(hi.z));
    hi.w = f2bf_rne(v.w); lo.w = f2bf_rne(v.w - bf2f(hi.w));
}

// Per-stage register prefetch: one 64x64 bf16 tile, hi+lo, both heads.
// 512 threads x 4 x 16B = 32 KB per stage.
struct Pre { bf16x8 v0, v1, v2, v3; };

__device__ __forceinline__ void stage_load(Pre& p,
        const unsigned short* __restrict__ H0, const unsigned short* __restrict__ L0,
        const unsigned short* __restrict__ H1, const unsigned short* __restrict__ L1,
        int colB, int kB, int t) {
    // thread t: row = t>>3 (0..63), k8 = t&7 -> 16B chunk; same (row,k8) for 4 arrays
    int off = (colB + (t >> 3)) * 256 + kB + (t & 7) * 8;
    p.v0 = *(const bf16x8*)&H0[off];
    p.v1 = *(const bf16x8*)&L0[off];
    p.v2 = *(const bf16x8*)&H1[off];
    p.v3 = *(const bf16x8*)&L1[off];
}
__device__ __forceinline__ void stage_write(const Pre& p, unsigned short* b, int t) {
    // b -> [head][hi/lo][64][LSB]; plane stride 64*72 = 4608 ushorts
    unsigned short* d = b + (t >> 3) * LSB + (t & 7) * 8;
    *(bf16x8*)(d        ) = p.v0;   // head0 hi
    *(bf16x8*)(d +  4608) = p.v1;   // head0 lo
    *(bf16x8*)(d +  9216) = p.v2;   // head1 hi
    *(bf16x8*)(d + 13824) = p.v3;   // head1 lo
}

// ---------------------------------------------------------------------------
// K0: grid 80. bids 0..63: split w1m/w1l/w2m/w2l (1024 elems each) into bf16
// hi/lo arrays. bids 64..79: moment partials over 64-row chunks (16 sets).
// Also zeroes out[0].
// ---------------------------------------------------------------------------
__global__ __launch_bounds__(256)
void k0_prep(const float* __restrict__ w1m, const float* __restrict__ w1l,
             const float* __restrict__ w2m, const float* __restrict__ w2l,
             const float* __restrict__ y, const float* __restrict__ z,
             unsigned short* __restrict__ w1mH, unsigned short* __restrict__ w1mL,
             unsigned short* __restrict__ w1lH, unsigned short* __restrict__ w1lL,
             unsigned short* __restrict__ w2mH, unsigned short* __restrict__ w2mL,
             unsigned short* __restrict__ w2lH, unsigned short* __restrict__ w2lL,
             float* __restrict__ pA1, float* __restrict__ pB1,
             float* __restrict__ out) {
    const int bid = blockIdx.x, t = threadIdx.x;
    if (bid < 64) {
        int off = bid * 1024 + t * 4;
        float4 v; ushort4 h4, l4;
        v = *(const float4*)&w1m[off]; split4(v, h4, l4);
        *(ushort4*)&w1mH[off] = h4; *(ushort4*)&w1mL[off] = l4;
        v = *(const float4*)&w1l[off]; split4(v, h4, l4);
        *(ushort4*)&w1lH[off] = h4; *(ushort4*)&w1lL[off] = l4;
        v = *(const float4*)&w2m[off]; split4(v, h4, l4);
        *(ushort4*)&w2mH[off] = h4; *(ushort4*)&w2mL[off] = l4;
        v = *(const float4*)&w2l[off]; split4(v, h4, l4);
        *(ushort4*)&w2lH[off] = h4; *(ushort4*)&w2lL[off] = l4;
    } else {
        int m = bid - 64;
        if (m == 0 && t == 0) out[0] = 0.f;   // consumed by KF atomics (K0->KF ordered)
        float sA = 0.f, sB = 0.f;
        int base = m * 64 * 256 + t;
        for (int j = 0; j < 64; j++) {
            float yv = y[base + j * 256];
            float zv = z[base + j * 256];
            sA += yv * yv + zv * zv;
            sB += yv + zv;
        }
        pA1[m * 256 + t] = sA;
        pB1[m * 256 + t] = sB;
    }
}

// ---------------------------------------------------------------------------
// KF: grid 64, 512 threads (8 waves). Block owns rows [bid*16, +16).
// Wave wv: head h = wv&1, ntile nt = wv>>1 (16 cols within each 64-col group).
// Layer1: x(LDS, split) @ w1^T  -> relu -> h split -> LDS Hb (never global).
// Layer2: Hb @ w2^T -> Cx exchange -> CLUB epilogue per 64-col group ->
// rowSum[16] -> relu -> block partial -> atomicAdd(out).
// 32 barrier'd stages, double-buffered Bt, reg prefetch issued one stage early.
// LDS: Ax 16.9K + Hb 33.8K + Bt 73.7K + Cx 8.7K + misc ~2K = 132 KB (<160).
// ---------------------------------------------------------------------------
__global__ __launch_bounds__(512)
void kf_fused(const float* __restrict__ x, const float* __restrict__ y, const float* __restrict__ z,
              const float* __restrict__ b1m, const float* __restrict__ b1l,
              const float* __restrict__ b2m, const float* __restrict__ b2l,
              const unsigned short* __restrict__ w1mH, const unsigned short* __restrict__ w1mL,
              const unsigned short* __restrict__ w1lH, const unsigned short* __restrict__ w1lL,
              const unsigned short* __restrict__ w2mH, const unsigned short* __restrict__ w2mL,
              const unsigned short* __restrict__ w2lH, const unsigned short* __restrict__ w2lL,
              const float* __restrict__ pA1, const float* __restrict__ pB1,
              float* __restrict__ out) {
    const int bid = blockIdx.x, t = threadIdx.x;
    const int R0 = bid << 4;
    const int lane = t & 63, quad = lane >> 4, mr = lane & 15;
    const int wv = t >> 6, h = wv & 1, nt = wv >> 1;

    __shared__ __align__(16) unsigned short Ax[2][16][264];      // x rows, hi/lo
    __shared__ __align__(16) unsigned short Hb[2][2][16][264];   // h: [head][hi/lo]
    __shared__ __align__(16) unsigned short BtF[2][18432];       // dbuf [head][hl][64][72]
    __shared__ float Cx[2][16][68];
    __shared__ float mAf[256], mBf[256], rowSum[16];

    // ---- phase A: moment fold, rowSum init, x stage+split ----
    if (t < 256) {
        float sA = 0.f, sB = 0.f;
#pragma unroll
        for (int sI = 0; sI < 16; sI++) { sA += pA1[sI * 256 + t]; sB += pB1[sI * 256 + t]; }
        mAf[t] = sA * (1.f / 1024.f);
        mBf[t] = sB * (1.f / 1024.f);
    }
    if (t < 16) rowSum[t] = 0.f;
#pragma unroll
    for (int p = 0; p < 2; p++) {
        int idx = p * 512 + t;
        int r = idx >> 6, k4 = idx & 63;
        float4 av = *(const float4*)&x[(R0 + r) * 256 + k4 * 4];
        ushort4 h4, l4; split4(av, h4, l4);
        *(ushort4*)&Ax[0][r][k4 * 4] = h4;
        *(ushort4*)&Ax[1][r][k4 * 4] = l4;
    }

    Pre pre;
    stage_load(pre, w1mH, w1mL, w1lH, w1lL, 0, 0, t);

    int s = 0;
    // ---- layer 1: h = relu(x @ w1^T + b1), kept in LDS ----
    for (int cg = 0; cg < 4; cg++) {
        f32x4 acc = {0.f, 0.f, 0.f, 0.f};
        for (int kt = 0; kt < 4; kt++, s++) {
            unsigned short* b = BtF[s & 1];
            stage_write(pre, b, t);
            if (s < 15) stage_load(pre, w1mH, w1mL, w1lH, w1lL,
                                   ((s + 1) >> 2) << 6, ((s + 1) & 3) << 6, t);
            else        stage_load(pre, w2mH, w2mL, w2lH, w2lL, 0, 0, t);
            __syncthreads();   // single barrier/stage: dbuf makes WAR safe
            const unsigned short* bHp = b + (h * 2 + 0) * 4608 + (nt * 16 + mr) * LSB;
            const unsigned short* bLp = b + (h * 2 + 1) * 4608 + (nt * 16 + mr) * LSB;
            const unsigned short* aHp = &Ax[0][mr][kt * 64];
            const unsigned short* aLp = &Ax[1][mr][kt * 64];
#pragma unroll
            for (int ks = 0; ks < 2; ks++) {
                int ko = ks * 32 + quad * 8;
                bf16x8 ah = *(const bf16x8*)&aHp[ko];
                bf16x8 al = *(const bf16x8*)&aLp[ko];
                bf16x8 bh = *(const bf16x8*)&bHp[ko];
                bf16x8 bl = *(const bf16x8*)&bLp[ko];
                acc = __builtin_amdgcn_mfma_f32_16x16x32_bf16(ah, bh, acc, 0, 0, 0);
                acc = __builtin_amdgcn_mfma_f32_16x16x32_bf16(ah, bl, acc, 0, 0, 0);
                acc = __builtin_amdgcn_mfma_f32_16x16x32_bf16(al, bh, acc, 0, 0, 0);
            }
        }
        // bias + relu -> split -> Hb (C/D: col=lane&15, row=quad*4+reg)
        int gcol = cg * 64 + nt * 16 + mr;
        float bb = (h ? b1l : b1m)[gcol];
#pragma unroll
        for (int reg = 0; reg < 4; reg++) {
            float v = fmaxf(acc[reg] + bb, 0.f);
            unsigned short hi = f2bf_rne(v);
            Hb[h][0][quad * 4 + reg][gcol] = hi;
            Hb[h][1][quad * 4 + reg][gcol] = f2bf_rne(v - bf2f(hi));
        }
    }

    // ---- layer 2 + CLUB epilogue, per 64-col group ----
    for (int cg = 0; cg < 4; cg++) {
        f32x4 acc = {0.f, 0.f, 0.f, 0.f};
        for (int kt = 0; kt < 4; kt++, s++) {
            unsigned short* b = BtF[s & 1];
            stage_write(pre, b, t);
            if (s < 31) {
                int nn = s - 15;  // next layer-2 stage index
                stage_load(pre, w2mH, w2mL, w2lH, w2lL, (nn >> 2) << 6, (nn & 3) << 6, t);
            }
            __syncthreads();     // also publishes Hb on the first layer-2 stage
            const unsigned short* bHp = b + (h * 2 + 0) * 4608 + (nt * 16 + mr) * LSB;
            const unsigned short* bLp = b + (h * 2 + 1) * 4608 + (nt * 16 + mr) * LSB;
            const unsigned short* aHp = &Hb[h][0][mr][kt * 64];
            const unsigned short* aLp = &Hb[h][1][mr][kt * 64];
#pragma unroll
            for (int ks = 0; ks < 2; ks++) {
                int ko = ks * 32 + quad * 8;
                bf16x8 ah = *(const bf16x8*)&aHp[ko];
                bf16x8 al = *(const bf16x8*)&aLp[ko];
                bf16x8 bh = *(const bf16x8*)&bHp[ko];
                bf16x8 bl = *(const bf16x8*)&bLp[ko];
                acc = __builtin_amdgcn_mfma_f32_16x16x32_bf16(ah, bh, acc, 0, 0, 0);
                acc = __builtin_amdgcn_mfma_f32_16x16x32_bf16(ah, bl, acc, 0, 0, 0);
                acc = __builtin_amdgcn_mfma_f32_16x16x32_bf16(al, bh, acc, 0, 0, 0);
            }
        }
        // exchange mu/lv for these 64 cols
        {
            float bb = (h ? b2l : b2m)[cg * 64 + nt * 16 + mr];
#pragma unroll
            for (int reg = 0; reg < 4; reg++)
                Cx[h][quad * 4 + reg][nt * 16 + mr] = acc[reg] + bb;
        }
        __syncthreads();
        // epilogue over 16x64 patch: thread = (row t>>5, col t&31, 2 cols strided 32)
        {
            int r = t >> 5, c0 = t & 31;
            float v = 0.f;
#pragma unroll
            for (int j = 0; j < 2; j++) {
                int c = c0 + 32 * j;
                int gcol = cg * 64 + c;
                float m  = Cx[0][r][c];
                float lv = tanhf(Cx[1][r][c]);
                float iv = 0.5f * expf(-lv);          // 1/(2*exp(logvar))
                int o = (R0 + r) * 256 + gcol;
                float yv = y[o], zv = z[o];
                float Mt = mAf[gcol] - 2.f * m * mBf[gcol] + 2.f * m * m;
                float dy = m - yv, dz = m - zv;
                v += iv * (Mt - dy * dy - dz * dz);
            }
#pragma unroll
            for (int msk = 16; msk; msk >>= 1)
                v += __shfl_xor(v, msk, 32);
            if (c0 == 0) rowSum[r] += v;
        }
        __syncthreads();   // rowSum done + Cx consumable before next cg overwrite
    }

    // ---- final: relu(rowSum) -> block partial -> one atomic into out ----
    if (t < 16) {
        float v = fmaxf(rowSum[t], 0.f);
#pragma unroll
        for (int msk = 8; msk; msk >>= 1)
            v += __shfl_xor(v, msk, 16);
        if (t == 0) atomicAdd(out, v * (1.f / 1024.f));
    }
}

// ---------------------------------------------------------------------------
extern "C" void kernel_launch(void* const* d_in, const int* in_sizes, int n_in,
                              void* d_out, int out_size, void* d_ws, size_t ws_size,
                              hipStream_t stream) {
    const float* x   = (const float*)d_in[0];
    const float* y   = (const float*)d_in[1];
    const float* zs  = (const float*)d_in[2];
    const float* w1m = (const float*)d_in[3];
    const float* b1m = (const float*)d_in[4];
    const float* w2m = (const float*)d_in[5];
    const float* b2m = (const float*)d_in[6];
    const float* w1l = (const float*)d_in[7];
    const float* b1l = (const float*)d_in[8];
    const float* w2l = (const float*)d_in[9];
    const float* b2l = (const float*)d_in[10];
    float* out = (float*)d_out;

    char* ws = (char*)d_ws;
    float* pA1 = (float*)(ws);                              // 16 KB
    float* pB1 = (float*)(ws + (64u  << 10));               // 16 KB
    unsigned short* w1mH = (unsigned short*)(ws + (128u  << 10));  // 128 KB each
    unsigned short* w1mL = (unsigned short*)(ws + (256u  << 10));
    unsigned short* w1lH = (unsigned short*)(ws + (384u  << 10));
    unsigned short* w1lL = (unsigned short*)(ws + (512u  << 10));
    unsigned short* w2mH = (unsigned short*)(ws + (640u  << 10));
    unsigned short* w2mL = (unsigned short*)(ws + (768u  << 10));
    unsigned short* w2lH = (unsigned short*)(ws + (896u  << 10));
    unsigned short* w2lL = (unsigned short*)(ws + (1024u << 10));

    k0_prep<<<80, 256, 0, stream>>>(w1m, w1l, w2m, w2l, y, zs,
                                    w1mH, w1mL, w1lH, w1lL,
                                    w2mH, w2mL, w2lH, w2lL,
                                    pA1, pB1, out);
    kf_fused<<<64, 512, 0, stream>>>(x, y, zs, b1m, b1l, b2m, b2l,
                                     w1mH, w1mL, w1lH, w1lL,
                                     w2mH, w2mL, w2lH, w2lL,
                                     pA1, pB1, out);
}

// Round 2
// 96.982 us; speedup vs baseline: 1.0129x; 1.0129x over previous
//
#include <hip/hip_runtime.h>
#include <math.h>

// N=1024, X_DIM=HID=Y_DIM=256.
// Round 2: revert to the proven 3-kernel round-0 structure (fused 1-block/CU
// version regressed), then remove ALL GEMM LDS staging: every operand is
// L2-resident (x 1MB, w1/w2 split ~1MB, h-split 2MB << 32MB aggregate L2), so
// fragments are loaded directly from global at MFMA fragment addresses
// (learn_hip common-mistake #7: LDS-staging L2-fit data is pure overhead).
// K1: zero LDS, zero barriers — fp32 loads + in-register Dekker split.
// K2: direct bf16x8 fragment loads; LDS only for Cx exchange + moment fold
// (2 barriers instead of 10). Numerics: identical k-order and MFMA order to
// round 0 -> bit-identical, absmax 0.0 expected.
// Rules kept: no cross-block fences/spins (R4/R9); fire-and-forget atomics OK.

typedef short bf16x8 __attribute__((ext_vector_type(8)));
typedef float f32x4  __attribute__((ext_vector_type(4)));

__device__ __forceinline__ unsigned short f2bf_rne(float f) {
    unsigned u = __float_as_uint(f);
    unsigned r = (u + 0x7fff + ((u >> 16) & 1)) >> 16;
    return (unsigned short)r;
}
__device__ __forceinline__ float bf2f(unsigned short h) {
    return __uint_as_float(((unsigned)h) << 16);
}
__device__ __forceinline__ void split4(float4 v, ushort4& hi, ushort4& lo) {
    hi.x = f2bf_rne(v.x); lo.x = f2bf_rne(v.x - bf2f(hi.x));
    hi.y = f2bf_rne(v.y); lo.y = f2bf_rne(v.y - bf2f(hi.y));
    hi.z = f2bf_rne(v.z); lo.z = f2bf_rne(v.z - bf2f(hi.z));
    hi.w = f2bf_rne(v.w); lo.w = f2bf_rne(v.w - bf2f(hi.w));
}
// Load 8 consecutive fp32 and Dekker-split into bf16 hi/lo fragments in-reg.
__device__ __forceinline__ void split8(const float* __restrict__ p,
                                       bf16x8& hi, bf16x8& lo) {
    float4 v0 = *(const float4*)p;
    float4 v1 = *(const float4*)(p + 4);
    float a[8] = {v0.x, v0.y, v0.z, v0.w, v1.x, v1.y, v1.z, v1.w};
#pragma unroll
    for (int i = 0; i < 8; i++) {
        unsigned short h = f2bf_rne(a[i]);
        hi[i] = (short)h;
        lo[i] = (short)f2bf_rne(a[i] - bf2f(h));
    }
}

// ---------------------------------------------------------------------------
// K1: grid 528. bids 0..511: layer-1 GEMM, 32x32 tile, K=256:
//   head=bid&1, ct=(bid>>1)&7 (32 cols), rt=bid>>4 (0..31, 32 rows);
//   wave w: mt=w&1 (16 rows), nt=w>>1 (16 cols).
// No LDS, no barriers: per-lane fp32 loads at fragment addresses + in-reg
// split. Same k-order (0..255) and MFMA order (hh,hl,lh) as round 0.
// bids 512..527: moment partials over 64-row chunks (16 sets).
// ---------------------------------------------------------------------------
__global__ __launch_bounds__(256, 2)
void k1_layer1(const float* __restrict__ x,
               const float* __restrict__ w1m, const float* __restrict__ w1l,
               const float* __restrict__ b1m, const float* __restrict__ b1l,
               const float* __restrict__ w2m, const float* __restrict__ w2l,
               unsigned short* __restrict__ hmH, unsigned short* __restrict__ hmL,
               unsigned short* __restrict__ hlH, unsigned short* __restrict__ hlL,
               unsigned short* __restrict__ w2mH, unsigned short* __restrict__ w2mL,
               unsigned short* __restrict__ w2lH, unsigned short* __restrict__ w2lL,
               const float* __restrict__ y, const float* __restrict__ z,
               float* __restrict__ pA1, float* __restrict__ pB1,
               float* __restrict__ rowAcc) {
    const int bid = blockIdx.x, t = threadIdx.x;

    if (bid >= 512) {   // moment block: rows [m*64, +64), thread = column
        int m = bid - 512;
        float sA = 0.f, sB = 0.f;
        int base = m * 64 * 256 + t;
        for (int j = 0; j < 64; j++) {
            float yv = y[base + j * 256];
            float zv = z[base + j * 256];
            sA += yv * yv + zv * zv;
            sB += yv + zv;
        }
        pA1[m * 256 + t] = sA;
        pB1[m * 256 + t] = sB;
        return;
    }

    const int head = bid & 1, ct = (bid >> 1) & 7, rt = bid >> 4;
    const int rowBase = rt * 32, colBase = ct * 32;
    const int w = t >> 6, lane = t & 63, quad = lane >> 4, mr = lane & 15;
    const int mt = w & 1, nt = w >> 1;

    const float* Bw   = head ? w1l : w1m;
    const float* bias = head ? b1l : b1m;
    unsigned short* CH = head ? hlH : hmH;
    unsigned short* CL = head ? hlL : hmL;

    const float* ax = &x [(rowBase + mt * 16 + mr) * 256];
    const float* bw = &Bw[(colBase + nt * 16 + mr) * 256];

    f32x4 acc = {0.f, 0.f, 0.f, 0.f};
#pragma unroll
    for (int ks = 0; ks < 8; ks++) {
        int k0 = ks * 32 + quad * 8;
        bf16x8 ah, al, bh, bl;
        split8(&ax[k0], ah, al);
        split8(&bw[k0], bh, bl);
        acc = __builtin_amdgcn_mfma_f32_16x16x32_bf16(ah, bh, acc, 0, 0, 0);
        acc = __builtin_amdgcn_mfma_f32_16x16x32_bf16(ah, bl, acc, 0, 0, 0);
        acc = __builtin_amdgcn_mfma_f32_16x16x32_bf16(al, bh, acc, 0, 0, 0);
    }

    // bias + relu -> Dekker split -> hi/lo stores (C/D: col=lane&15, row=quad*4+reg)
    {
        int cg = colBase + nt * 16 + mr;
        float bb = bias[cg];
#pragma unroll
        for (int reg = 0; reg < 4; reg++) {
            int rg = rowBase + mt * 16 + quad * 4 + reg;
            float v = fmaxf(acc[reg] + bb, 0.f);
            unsigned short hi = f2bf_rne(v);
            CH[rg * 256 + cg] = hi;
            CL[rg * 256 + cg] = f2bf_rne(v - bf2f(hi));
        }
    }

    // w2 pre-split (blocks 0..255 cover 256x256)
    if (bid < 256) {
        int off = bid * 256 + t;
        float vm = w2m[off], vl = w2l[off];
        unsigned short h1 = f2bf_rne(vm);
        w2mH[off] = h1; w2mL[off] = f2bf_rne(vm - bf2f(h1));
        unsigned short h2 = f2bf_rne(vl);
        w2lH[off] = h2; w2lL[off] = f2bf_rne(vl - bf2f(h2));
    }

    // zero rowAcc (consumed by K2 across the kernel boundary)
    if (bid < 4) rowAcc[bid * 256 + t] = 0.f;
}

// ---------------------------------------------------------------------------
// K2: layer-2 GEMM, both heads, 32(rows)x16(cols) patch, K=256. 512 blocks =
// 32 rt x 16 ct. Wave w: head=w&1, mt=w>>1 (16 rows), single 16-col ntile.
// Direct bf16x8 fragment loads from the L2-resident split arrays — no A/B
// LDS staging, 2 barriers total. Cx exchange + in-block CLUB epilogue as
// round 0; moment fold reads 16 partial sets (one load/thread).
// ---------------------------------------------------------------------------
__global__ __launch_bounds__(256, 2)
void k2_fused(const unsigned short* __restrict__ hmH, const unsigned short* __restrict__ hmL,
              const unsigned short* __restrict__ hlH, const unsigned short* __restrict__ hlL,
              const unsigned short* __restrict__ w2mH, const unsigned short* __restrict__ w2mL,
              const unsigned short* __restrict__ w2lH, const unsigned short* __restrict__ w2lL,
              const float* __restrict__ b2m, const float* __restrict__ b2l,
              const float* __restrict__ y, const float* __restrict__ z,
              const float* __restrict__ pA1, const float* __restrict__ pB1,
              float* __restrict__ rowAcc) {
    const int bid = blockIdx.x, t = threadIdx.x;
    const int rt = bid >> 4, ct = bid & 15;
    const int rowBase = rt * 32, colBase = ct * 16;
    const int w = t >> 6, lane = t & 63, quad = lane >> 4, mr = lane & 15;
    const int h = w & 1, mt = w >> 1;

    __shared__ float Cx[2][32][17];
    __shared__ float partA[16][16], partB[16][16];
    __shared__ float mAf[16], mBf[16];

    // ---- moment fold: 16 partial sets -> means for this block's 16 cols ----
    {
        int s = t >> 4, c = t & 15;      // one load per thread
        partA[s][c] = pA1[s * 256 + colBase + c];
        partB[s][c] = pB1[s * 256 + colBase + c];
    }
    __syncthreads();
    if (t < 16) {
        float sA = 0.f, sB = 0.f;
#pragma unroll
        for (int s = 0; s < 16; s++) { sA += partA[s][t]; sB += partB[s][t]; }
        mAf[t] = sA * (1.f / 1024.f);
        mBf[t] = sB * (1.f / 1024.f);
    }

    // ---- GEMM: direct fragment loads, no staging, no barriers ----
    const unsigned short* AH = h ? hlH : hmH;
    const unsigned short* AL = h ? hlL : hmL;
    const unsigned short* BH = h ? w2lH : w2mH;
    const unsigned short* BL = h ? w2lL : w2mL;
    const unsigned short* aH = &AH[(rowBase + mt * 16 + mr) * 256];
    const unsigned short* aL = &AL[(rowBase + mt * 16 + mr) * 256];
    const unsigned short* bH = &BH[(colBase + mr) * 256];
    const unsigned short* bL = &BL[(colBase + mr) * 256];

    f32x4 acc = {0.f, 0.f, 0.f, 0.f};
#pragma unroll
    for (int ks = 0; ks < 8; ks++) {
        int k0 = ks * 32 + quad * 8;
        bf16x8 ah = *(const bf16x8*)&aH[k0];
        bf16x8 al = *(const bf16x8*)&aL[k0];
        bf16x8 bh = *(const bf16x8*)&bH[k0];
        bf16x8 bl = *(const bf16x8*)&bL[k0];
        acc = __builtin_amdgcn_mfma_f32_16x16x32_bf16(ah, bh, acc, 0, 0, 0);
        acc = __builtin_amdgcn_mfma_f32_16x16x32_bf16(ah, bl, acc, 0, 0, 0);
        acc = __builtin_amdgcn_mfma_f32_16x16x32_bf16(al, bh, acc, 0, 0, 0);
    }

    // ---- exchange mu/lv via LDS (C/D: col=lane&15, row=quad*4+reg) ----
    {
        const float* bias = h ? b2l : b2m;
        float bb = bias[colBase + mr];
#pragma unroll
        for (int reg = 0; reg < 4; reg++)
            Cx[h][mt * 16 + quad * 4 + reg][mr] = acc[reg] + bb;
    }
    __syncthreads();

    // ---- in-block CLUB epilogue: 32x16 patch; reduce 16 cols -> rowAcc ----
    {
        int col = t & 15, rg = t >> 4;        // rg 0..15, 2 rows each
        int gcol = colBase + col;
        float mA = mAf[col], mB = mBf[col];
#pragma unroll
        for (int rr = 0; rr < 2; rr++) {
            int row = rg * 2 + rr;
            int o = (rowBase + row) * 256 + gcol;
            float m  = Cx[0][row][col];
            float lv = tanhf(Cx[1][row][col]);
            float iv = 0.5f * expf(-lv);      // 1/(2*exp(logvar))
            float yv = y[o];
            float zv = z[o];
            float Mt = mA - 2.f * m * mB + 2.f * m * m;
            float dy = m - yv, dz = m - zv;
            float term = iv * (Mt - dy * dy - dz * dz);
#pragma unroll
            for (int msk = 8; msk; msk >>= 1)
                term += __shfl_xor(term, msk, 16);
            if (col == 0) atomicAdd(&rowAcc[rowBase + row], term);  // no fence
        }
    }
}

// ---------------------------------------------------------------------------
// K3: 1 block. out = mean_i relu(rowAcc[i]).
// ---------------------------------------------------------------------------
__global__ __launch_bounds__(256)
void k3_final(const float* __restrict__ rowAcc, float* __restrict__ out) {
    __shared__ float red[4];
    int t = threadIdx.x, lane = t & 63, wave = t >> 6;
    float v = 0.f;
#pragma unroll
    for (int p = 0; p < 4; p++)
        v += fmaxf(rowAcc[p * 256 + t], 0.f);
#pragma unroll
    for (int msk = 32; msk; msk >>= 1)
        v += __shfl_xor(v, msk, 64);
    if (lane == 0) red[wave] = v;
    __syncthreads();
    if (t == 0)
        out[0] = (red[0] + red[1] + red[2] + red[3]) * (1.f / 1024.f);
}

// ---------------------------------------------------------------------------
extern "C" void kernel_launch(void* const* d_in, const int* in_sizes, int n_in,
                              void* d_out, int out_size, void* d_ws, size_t ws_size,
                              hipStream_t stream) {
    const float* x   = (const float*)d_in[0];
    const float* y   = (const float*)d_in[1];
    const float* zs  = (const float*)d_in[2];
    const float* w1m = (const float*)d_in[3];
    const float* b1m = (const float*)d_in[4];
    const float* w2m = (const float*)d_in[5];
    const float* b2m = (const float*)d_in[6];
    const float* w1l = (const float*)d_in[7];
    const float* b1l = (const float*)d_in[8];
    const float* w2l = (const float*)d_in[9];
    const float* b2l = (const float*)d_in[10];
    float* out = (float*)d_out;

    char* ws = (char*)d_ws;
    float* pA1    = (float*)(ws);                      // 16x256 f32 = 16 KB
    float* pB1    = (float*)(ws + (256u << 10));       // 16 KB
    float* rowAcc = (float*)(ws + (512u << 10));       // 4 KB
    unsigned short* hmH = (unsigned short*)(ws + (1024u << 10));  // 512 KB each
    unsigned short* hmL = (unsigned short*)(ws + (1536u << 10));
    unsigned short* hlH = (unsigned short*)(ws + (2048u << 10));
    unsigned short* hlL = (unsigned short*)(ws + (2560u << 10));
    unsigned short* w2mH = (unsigned short*)(ws + (3072u << 10)); // 128 KB each
    unsigned short* w2mL = (unsigned short*)(ws + (3200u << 10));
    unsigned short* w2lH = (unsigned short*)(ws + (3328u << 10));
    unsigned short* w2lL = (unsigned short*)(ws + (3456u << 10));

    k1_layer1<<<528, 256, 0, stream>>>(x, w1m, w1l, b1m, b1l, w2m, w2l,
                                       hmH, hmL, hlH, hlL,
                                       w2mH, w2mL, w2lH, w2lL,
                                       y, zs, pA1, pB1, rowAcc);
    k2_fused<<<512, 256, 0, stream>>>(hmH, hmL, hlH, hlL,
                                      w2mH, w2mL, w2lH, w2lL,
                                      b2m, b2l, y, zs, pA1, pB1, rowAcc);
    k3_final<<<1, 256, 0, stream>>>(rowAcc, out);
}

// Round 3
// 91.445 us; speedup vs baseline: 1.0743x; 1.0606x over previous
//
#include <hip/hip_runtime.h>
#include <math.h>

// N=1024, X_DIM=HID=Y_DIM=256.
// Round 3: revert to proven round-0 3-kernel structure (92.1 us; rounds 1/2
// alternatives both regressed), with three targeted fixes:
//  (a) K1 grid 528 -> 512: moment partials folded into GEMM blocks bid<64
//      (64 sets x 16 rows) — kills the 16-block serial tail past the
//      2-blocks/CU x 256-CU = 512 resident slots.
//  (b) K1 stages the FULL 32x256 K-extent once (67.6 KB LDS, still 2/CU):
//      1 barrier instead of 8. Same k-order + MFMA order -> bit-identical.
//  (c) K2 moment fold reads 64 partial sets (4 loads/thread).
// Lessons kept: LDS staging beats direct-L2 fragment loads here (R2 post-
// mortem: latency-bound, stage+split amortizes); no cross-block fences/spins;
// fire-and-forget atomics fine; occupancy lever saturates at 2 blocks/CU.
constexpr int LSK = 264;  // bf16 LDS row stride for K=256 tiles (528 B = 4-bank
                          // row offset — same benign banking as proven LSB=72)

typedef short bf16x8 __attribute__((ext_vector_type(8)));
typedef float f32x4  __attribute__((ext_vector_type(4)));

__device__ __forceinline__ unsigned short f2bf_rne(float f) {
    unsigned u = __float_as_uint(f);
    unsigned r = (u + 0x7fff + ((u >> 16) & 1)) >> 16;
    return (unsigned short)r;
}
__device__ __forceinline__ float bf2f(unsigned short h) {
    return __uint_as_float(((unsigned)h) << 16);
}
__device__ __forceinline__ void split4(float4 v, ushort4& hi, ushort4& lo) {
    hi.x = f2bf_rne(v.x); lo.x = f2bf_rne(v.x - bf2f(hi.x));
    hi.y = f2bf_rne(v.y); lo.y = f2bf_rne(v.y - bf2f(hi.y));
    hi.z = f2bf_rne(v.z); lo.z = f2bf_rne(v.z - bf2f(hi.z));
    hi.w = f2bf_rne(v.w); lo.w = f2bf_rne(v.w - bf2f(hi.w));
}

// ---------------------------------------------------------------------------
// K1: grid 512. Layer-1 GEMM, 32x32 tile, K=256:
//   head=bid&1, ct=(bid>>1)&7 (32 cols), rt=bid>>4 (0..31, 32 rows);
//   wave w: mt=w&1 (16 rows), nt=w>>1 (16 cols).
// Full-K staging: one cooperative stage+split of A(x) and B(w1) 32x256 fp32
// tiles into bf16 hi/lo LDS, ONE barrier, then 8 ks x 3 MFMA straight.
// Extra duties: bid<64 moment partials (16 rows each), bid<256 w2 pre-split,
// bid<4 zero rowAcc.
// ---------------------------------------------------------------------------
__global__ __launch_bounds__(256, 2)
void k1_layer1(const float* __restrict__ x,
               const float* __restrict__ w1m, const float* __restrict__ w1l,
               const float* __restrict__ b1m, const float* __restrict__ b1l,
               const float* __restrict__ w2m, const float* __restrict__ w2l,
               unsigned short* __restrict__ hmH, unsigned short* __restrict__ hmL,
               unsigned short* __restrict__ hlH, unsigned short* __restrict__ hlL,
               unsigned short* __restrict__ w2mH, unsigned short* __restrict__ w2mL,
               unsigned short* __restrict__ w2lH, unsigned short* __restrict__ w2lL,
               const float* __restrict__ y, const float* __restrict__ z,
               float* __restrict__ pA1, float* __restrict__ pB1,
               float* __restrict__ rowAcc) {
    const int bid = blockIdx.x, t = threadIdx.x;

    const int head = bid & 1, ct = (bid >> 1) & 7, rt = bid >> 4;
    const int rowBase = rt * 32, colBase = ct * 32;
    const int w = t >> 6, lane = t & 63, quad = lane >> 4, mr = lane & 15;
    const int mt = w & 1, nt = w >> 1;

    const float* Bw   = head ? w1l : w1m;
    const float* bias = head ? b1l : b1m;
    unsigned short* CH = head ? hlH : hmH;
    unsigned short* CL = head ? hlL : hmL;

    __shared__ __align__(16) unsigned short Ah[32][LSK], Al[32][LSK];
    __shared__ __align__(16) unsigned short Bh[32][LSK], Bl[32][LSK];

    // ---- stage full 32x256 A and B tiles, split to bf16 hi/lo ----
#pragma unroll
    for (int p = 0; p < 8; p++) {
        int idx = p * 256 + t;            // 0..2047
        int r = idx >> 6, k4 = idx & 63;  // row, float4-unit
        float4 av = *(const float4*)&x [(rowBase + r) * 256 + k4 * 4];
        float4 bv = *(const float4*)&Bw[(colBase + r) * 256 + k4 * 4];
        ushort4 h4, l4;
        split4(av, h4, l4);
        *(ushort4*)&Ah[r][k4 * 4] = h4;
        *(ushort4*)&Al[r][k4 * 4] = l4;
        split4(bv, h4, l4);
        *(ushort4*)&Bh[r][k4 * 4] = h4;
        *(ushort4*)&Bl[r][k4 * 4] = l4;
    }
    __syncthreads();                      // the only barrier in K1

    // ---- 8 k-slices x 3 MFMA (same order as proven: k ascending, hh,hl,lh) --
    const unsigned short* aHp = &Ah[mt * 16 + mr][0];
    const unsigned short* aLp = &Al[mt * 16 + mr][0];
    const unsigned short* bHp = &Bh[nt * 16 + mr][0];
    const unsigned short* bLp = &Bl[nt * 16 + mr][0];

    f32x4 acc = {0.f, 0.f, 0.f, 0.f};
#pragma unroll
    for (int ks = 0; ks < 8; ks++) {
        int ko = ks * 32 + quad * 8;
        bf16x8 ah = *(const bf16x8*)&aHp[ko];
        bf16x8 al = *(const bf16x8*)&aLp[ko];
        bf16x8 bh = *(const bf16x8*)&bHp[ko];
        bf16x8 bl = *(const bf16x8*)&bLp[ko];
        acc = __builtin_amdgcn_mfma_f32_16x16x32_bf16(ah, bh, acc, 0, 0, 0);
        acc = __builtin_amdgcn_mfma_f32_16x16x32_bf16(ah, bl, acc, 0, 0, 0);
        acc = __builtin_amdgcn_mfma_f32_16x16x32_bf16(al, bh, acc, 0, 0, 0);
    }

    // bias + relu -> Dekker split -> hi/lo stores (C/D: col=lane&15, row=quad*4+reg)
    {
        int cg = colBase + nt * 16 + mr;
        float bb = bias[cg];
#pragma unroll
        for (int reg = 0; reg < 4; reg++) {
            int rg = rowBase + mt * 16 + quad * 4 + reg;
            float v = fmaxf(acc[reg] + bb, 0.f);
            unsigned short hi = f2bf_rne(v);
            CH[rg * 256 + cg] = hi;
            CL[rg * 256 + cg] = f2bf_rne(v - bf2f(hi));
        }
    }

    // w2 pre-split (blocks 0..255 cover 256x256)
    if (bid < 256) {
        int off = bid * 256 + t;
        float vm = w2m[off], vl = w2l[off];
        unsigned short h1 = f2bf_rne(vm);
        w2mH[off] = h1; w2mL[off] = f2bf_rne(vm - bf2f(h1));
        unsigned short h2 = f2bf_rne(vl);
        w2lH[off] = h2; w2lL[off] = f2bf_rne(vl - bf2f(h2));
    }

    // moment partials: bid<64 each covers rows [bid*16, +16), thread = column
    if (bid < 64) {
        float sA = 0.f, sB = 0.f;
        int base = bid * 16 * 256 + t;
#pragma unroll 4
        for (int j = 0; j < 16; j++) {
            float yv = y[base + j * 256];
            float zv = z[base + j * 256];
            sA += yv * yv + zv * zv;
            sB += yv + zv;
        }
        pA1[bid * 256 + t] = sA;
        pB1[bid * 256 + t] = sB;
    }

    // zero rowAcc (consumed by K2 across the kernel boundary)
    if (bid < 4) rowAcc[bid * 256 + t] = 0.f;
}

// ---------------------------------------------------------------------------
// K2: layer-2 GEMM, both heads, 32(rows)x16(cols) patch, K=256,
// conversion-free + in-block CLUB epilogue. 512 blocks = 32 rt x 16 ct.
// Wave w: head=w&1, mt=w>>1 (16 rows), single 16-col ntile. (Round-0 proven.)
// Moment fold now reads 64 partial sets (4 loads/thread).
// ---------------------------------------------------------------------------
constexpr int LSB = 72;  // bf16 LDS row stride (144 B) — benign banks

__global__ __launch_bounds__(256, 2)
void k2_fused(const unsigned short* __restrict__ hmH, const unsigned short* __restrict__ hmL,
              const unsigned short* __restrict__ hlH, const unsigned short* __restrict__ hlL,
              const unsigned short* __restrict__ w2mH, const unsigned short* __restrict__ w2mL,
              const unsigned short* __restrict__ w2lH, const unsigned short* __restrict__ w2lL,
              const float* __restrict__ b2m, const float* __restrict__ b2l,
              const float* __restrict__ y, const float* __restrict__ z,
              const float* __restrict__ pA1, const float* __restrict__ pB1,
              float* __restrict__ rowAcc) {
    const int bid = blockIdx.x, t = threadIdx.x;
    const int rt = bid >> 4, ct = bid & 15;
    const int rowBase = rt * 32, colBase = ct * 16;
    const int w = t >> 6, lane = t & 63, quad = lane >> 4, mr = lane & 15;
    const int h = w & 1, mt = w >> 1;

    __shared__ __align__(16) unsigned short Ast[2][2][32][LSB];  // [head][hi/lo]
    __shared__ __align__(16) unsigned short Bst[2][2][16][LSB];
    __shared__ float Cx[2][32][17];
    __shared__ float partA[16][16], partB[16][16];
    __shared__ float mAf[16], mBf[16];

    const unsigned short* Aarr[4] = {hmH, hmL, hlH, hlL};
    const unsigned short* Barr[4] = {w2mH, w2mL, w2lH, w2lL};

    // ---- moment fold: 64 partial sets -> means for this block's 16 cols ----
    {
        int s = t >> 4, c = t & 15;      // 4 loads per thread (sets 4s..4s+3)
        float a0 = 0.f, b0 = 0.f;
#pragma unroll
        for (int j = 0; j < 4; j++) {
            a0 += pA1[(s * 4 + j) * 256 + colBase + c];
            b0 += pB1[(s * 4 + j) * 256 + colBase + c];
        }
        partA[s][c] = a0;
        partB[s][c] = b0;
    }
    __syncthreads();
    if (t < 16) {
        float sA = 0.f, sB = 0.f;
#pragma unroll
        for (int s = 0; s < 16; s++) { sA += partA[s][t]; sB += partB[s][t]; }
        mAf[t] = sA * (1.f / 1024.f);
        mBf[t] = sB * (1.f / 1024.f);
    }

    f32x4 acc = {0.f, 0.f, 0.f, 0.f};

    for (int kt = 0; kt < 256; kt += 64) {
#pragma unroll
        for (int hp = 0; hp < 4; hp++) {    // head*2 + (hi/lo)
            // A: 32 rows x 16 k4-units = 512 ushort4 -> 2 iters
#pragma unroll
            for (int p = 0; p < 2; p++) {
                int idx = p * 256 + t;
                int r = idx >> 4, k4 = idx & 15;
                *(ushort4*)&Ast[hp >> 1][hp & 1][r][k4 * 4] =
                    *(const ushort4*)&Aarr[hp][(rowBase + r) * 256 + kt + k4 * 4];
            }
            // B: 16 rows x 16 k4-units = 256 ushort4 -> 1 iter
            {
                int r = t >> 4, k4 = t & 15;
                *(ushort4*)&Bst[hp >> 1][hp & 1][r][k4 * 4] =
                    *(const ushort4*)&Barr[hp][(colBase + r) * 256 + kt + k4 * 4];
            }
        }
        __syncthreads();

#pragma unroll
        for (int kk = 0; kk < 64; kk += 32) {
            int ko = kk + quad * 8;
            bf16x8 ah = *(const bf16x8*)&Ast[h][0][mt * 16 + mr][ko];
            bf16x8 al = *(const bf16x8*)&Ast[h][1][mt * 16 + mr][ko];
            bf16x8 bh = *(const bf16x8*)&Bst[h][0][mr][ko];
            bf16x8 bl = *(const bf16x8*)&Bst[h][1][mr][ko];
            acc = __builtin_amdgcn_mfma_f32_16x16x32_bf16(ah, bh, acc, 0, 0, 0);
            acc = __builtin_amdgcn_mfma_f32_16x16x32_bf16(ah, bl, acc, 0, 0, 0);
            acc = __builtin_amdgcn_mfma_f32_16x16x32_bf16(al, bh, acc, 0, 0, 0);
        }
        __syncthreads();
    }

    // ---- exchange mu/lv via LDS (C/D: col=lane&15, row=quad*4+reg) ----
    {
        const float* bias = h ? b2l : b2m;
        float bb = bias[colBase + mr];
#pragma unroll
        for (int reg = 0; reg < 4; reg++)
            Cx[h][mt * 16 + quad * 4 + reg][mr] = acc[reg] + bb;
    }
    __syncthreads();

    // ---- in-block CLUB epilogue: 32x16 patch; reduce 16 cols -> rowAcc ----
    {
        int col = t & 15, rg = t >> 4;        // rg 0..15, 2 rows each
        int gcol = colBase + col;
        float mA = mAf[col], mB = mBf[col];
#pragma unroll
        for (int rr = 0; rr < 2; rr++) {
            int row = rg * 2 + rr;
            int o = (rowBase + row) * 256 + gcol;
            float m  = Cx[0][row][col];
            float lv = tanhf(Cx[1][row][col]);
            float iv = 0.5f * expf(-lv);      // 1/(2*exp(logvar))
            float yv = y[o];
            float zv = z[o];
            float Mt = mA - 2.f * m * mB + 2.f * m * m;
            float dy = m - yv, dz = m - zv;
            float term = iv * (Mt - dy * dy - dz * dz);
#pragma unroll
            for (int msk = 8; msk; msk >>= 1)
                term += __shfl_xor(term, msk, 16);
            if (col == 0) atomicAdd(&rowAcc[rowBase + row], term);  // no fence
        }
    }
}

// ---------------------------------------------------------------------------
// K3: 1 block. out = mean_i relu(rowAcc[i]).
// ---------------------------------------------------------------------------
__global__ __launch_bounds__(256)
void k3_final(const float* __restrict__ rowAcc, float* __restrict__ out) {
    __shared__ float red[4];
    int t = threadIdx.x, lane = t & 63, wave = t >> 6;
    float v = 0.f;
#pragma unroll
    for (int p = 0; p < 4; p++)
        v += fmaxf(rowAcc[p * 256 + t], 0.f);
#pragma unroll
    for (int msk = 32; msk; msk >>= 1)
        v += __shfl_xor(v, msk, 64);
    if (lane == 0) red[wave] = v;
    __syncthreads();
    if (t == 0)
        out[0] = (red[0] + red[1] + red[2] + red[3]) * (1.f / 1024.f);
}

// ---------------------------------------------------------------------------
extern "C" void kernel_launch(void* const* d_in, const int* in_sizes, int n_in,
                              void* d_out, int out_size, void* d_ws, size_t ws_size,
                              hipStream_t stream) {
    const float* x   = (const float*)d_in[0];
    const float* y   = (const float*)d_in[1];
    const float* zs  = (const float*)d_in[2];
    const float* w1m = (const float*)d_in[3];
    const float* b1m = (const float*)d_in[4];
    const float* w2m = (const float*)d_in[5];
    const float* b2m = (const float*)d_in[6];
    const float* w1l = (const float*)d_in[7];
    const float* b1l = (const float*)d_in[8];
    const float* w2l = (const float*)d_in[9];
    const float* b2l = (const float*)d_in[10];
    float* out = (float*)d_out;

    char* ws = (char*)d_ws;
    float* pA1    = (float*)(ws);                      // 64x256 f32 = 64 KB
    float* pB1    = (float*)(ws + (256u << 10));       // 64 KB
    float* rowAcc = (float*)(ws + (512u << 10));       // 4 KB
    unsigned short* hmH = (unsigned short*)(ws + (1024u << 10));  // 512 KB each
    unsigned short* hmL = (unsigned short*)(ws + (1536u << 10));
    unsigned short* hlH = (unsigned short*)(ws + (2048u << 10));
    unsigned short* hlL = (unsigned short*)(ws + (2560u << 10));
    unsigned short* w2mH = (unsigned short*)(ws + (3072u << 10)); // 128 KB each
    unsigned short* w2mL = (unsigned short*)(ws + (3200u << 10));
    unsigned short* w2lH = (unsigned short*)(ws + (3328u << 10));
    unsigned short* w2lL = (unsigned short*)(ws + (3456u << 10));

    k1_layer1<<<512, 256, 0, stream>>>(x, w1m, w1l, b1m, b1l, w2m, w2l,
                                       hmH, hmL, hlH, hlL,
                                       w2mH, w2mL, w2lH, w2lL,
                                       y, zs, pA1, pB1, rowAcc);
    k2_fused<<<512, 256, 0, stream>>>(hmH, hmL, hlH, hlL,
                                      w2mH, w2mL, w2lH, w2lL,
                                      b2m, b2l, y, zs, pA1, pB1, rowAcc);
    k3_final<<<1, 256, 0, stream>>>(rowAcc, out);
}

// Round 4
// 90.815 us; speedup vs baseline: 1.0817x; 1.0069x over previous
//
#include <hip/hip_runtime.h>
#include <math.h>

// N=1024, X_DIM=HID=Y_DIM=256.
// Round 4: keep round-3 skeleton (91.4 us, best). Three changes:
//  (a) K2: double-buffered staging + register prefetch -> 5 barriers (was 10);
//      kt+1 loads issue under kt's MFMAs.
//  (b) w2 pre-split removed from K1 (256-block store tail gone, -1MB global
//      writes); K2 splits w2 fp32 in-register during B staging (same split4
//      arithmetic -> bit-identical fragments).
//  (c) K1 moments on bid>=384 (128 sets x 8 rows), issued BEFORE staging so
//      loads hide under it; K2 fold = 8 loads/thread, zero dedicated barriers
//      (fold after kt loop, consumed after Cx barrier).
// Lessons kept: LDS staging beats direct-L2 fragment loads (R2); fused
// 1-launch regressed (R1); 2 blocks/CU saturates; no cross-block fences.
constexpr int LSK = 264;  // K1 full-K row stride (proven benign banking)
constexpr int LSB = 72;   // K2 64-k row stride (proven benign banking)

typedef short bf16x8 __attribute__((ext_vector_type(8)));
typedef float f32x4  __attribute__((ext_vector_type(4)));

__device__ __forceinline__ unsigned short f2bf_rne(float f) {
    unsigned u = __float_as_uint(f);
    unsigned r = (u + 0x7fff + ((u >> 16) & 1)) >> 16;
    return (unsigned short)r;
}
__device__ __forceinline__ float bf2f(unsigned short h) {
    return __uint_as_float(((unsigned)h) << 16);
}
__device__ __forceinline__ void split4(float4 v, ushort4& hi, ushort4& lo) {
    hi.x = f2bf_rne(v.x); lo.x = f2bf_rne(v.x - bf2f(hi.x));
    hi.y = f2bf_rne(v.y); lo.y = f2bf_rne(v.y - bf2f(hi.y));
    hi.z = f2bf_rne(v.z); lo.z = f2bf_rne(v.z - bf2f(hi.z));
    hi.w = f2bf_rne(v.w); lo.w = f2bf_rne(v.w - bf2f(hi.w));
}

// ---------------------------------------------------------------------------
// K1: grid 512. Layer-1 GEMM, 32x32 tile, K=256 (round-3 proven):
//   head=bid&1, ct=(bid>>1)&7, rt=bid>>4; wave w: mt=w&1, nt=w>>1.
// Full-K staging, ONE barrier. Extra duties: bid>=384 moment partials
// (8 rows each, issued before staging), bid<4 zero rowAcc. No w2 duty.
// ---------------------------------------------------------------------------
__global__ __launch_bounds__(256, 2)
void k1_layer1(const float* __restrict__ x,
               const float* __restrict__ w1m, const float* __restrict__ w1l,
               const float* __restrict__ b1m, const float* __restrict__ b1l,
               unsigned short* __restrict__ hmH, unsigned short* __restrict__ hmL,
               unsigned short* __restrict__ hlH, unsigned short* __restrict__ hlL,
               const float* __restrict__ y, const float* __restrict__ z,
               float* __restrict__ pA1, float* __restrict__ pB1,
               float* __restrict__ rowAcc) {
    const int bid = blockIdx.x, t = threadIdx.x;

    const int head = bid & 1, ct = (bid >> 1) & 7, rt = bid >> 4;
    const int rowBase = rt * 32, colBase = ct * 32;
    const int w = t >> 6, lane = t & 63, quad = lane >> 4, mr = lane & 15;
    const int mt = w & 1, nt = w >> 1;

    const float* Bw   = head ? w1l : w1m;
    const float* bias = head ? b1l : b1m;
    unsigned short* CH = head ? hlH : hmH;
    unsigned short* CL = head ? hlL : hmL;

    __shared__ __align__(16) unsigned short Ah[32][LSK], Al[32][LSK];
    __shared__ __align__(16) unsigned short Bh[32][LSK], Bl[32][LSK];

    // ---- moment partials first (bid>=384): rows [m*8, +8), thread = column.
    // Loads issue before staging; FMAs retire under the staging latency.
    if (bid >= 384) {
        int m = bid - 384;
        float sA = 0.f, sB = 0.f;
        int base = m * 8 * 256 + t;
#pragma unroll
        for (int j = 0; j < 8; j++) {
            float yv = y[base + j * 256];
            float zv = z[base + j * 256];
            sA += yv * yv + zv * zv;
            sB += yv + zv;
        }
        pA1[m * 256 + t] = sA;
        pB1[m * 256 + t] = sB;
    }

    // ---- stage full 32x256 A and B tiles, split to bf16 hi/lo ----
#pragma unroll
    for (int p = 0; p < 8; p++) {
        int idx = p * 256 + t;            // 0..2047
        int r = idx >> 6, k4 = idx & 63;  // row, float4-unit
        float4 av = *(const float4*)&x [(rowBase + r) * 256 + k4 * 4];
        float4 bv = *(const float4*)&Bw[(colBase + r) * 256 + k4 * 4];
        ushort4 h4, l4;
        split4(av, h4, l4);
        *(ushort4*)&Ah[r][k4 * 4] = h4;
        *(ushort4*)&Al[r][k4 * 4] = l4;
        split4(bv, h4, l4);
        *(ushort4*)&Bh[r][k4 * 4] = h4;
        *(ushort4*)&Bl[r][k4 * 4] = l4;
    }
    __syncthreads();                      // the only barrier in K1

    const unsigned short* aHp = &Ah[mt * 16 + mr][0];
    const unsigned short* aLp = &Al[mt * 16 + mr][0];
    const unsigned short* bHp = &Bh[nt * 16 + mr][0];
    const unsigned short* bLp = &Bl[nt * 16 + mr][0];

    f32x4 acc = {0.f, 0.f, 0.f, 0.f};
#pragma unroll
    for (int ks = 0; ks < 8; ks++) {
        int ko = ks * 32 + quad * 8;
        bf16x8 ah = *(const bf16x8*)&aHp[ko];
        bf16x8 al = *(const bf16x8*)&aLp[ko];
        bf16x8 bh = *(const bf16x8*)&bHp[ko];
        bf16x8 bl = *(const bf16x8*)&bLp[ko];
        acc = __builtin_amdgcn_mfma_f32_16x16x32_bf16(ah, bh, acc, 0, 0, 0);
        acc = __builtin_amdgcn_mfma_f32_16x16x32_bf16(ah, bl, acc, 0, 0, 0);
        acc = __builtin_amdgcn_mfma_f32_16x16x32_bf16(al, bh, acc, 0, 0, 0);
    }

    // bias + relu -> Dekker split -> hi/lo stores (C/D: col=lane&15, row=quad*4+reg)
    {
        int cg = colBase + nt * 16 + mr;
        float bb = bias[cg];
#pragma unroll
        for (int reg = 0; reg < 4; reg++) {
            int rg = rowBase + mt * 16 + quad * 4 + reg;
            float v = fmaxf(acc[reg] + bb, 0.f);
            unsigned short hi = f2bf_rne(v);
            CH[rg * 256 + cg] = hi;
            CL[rg * 256 + cg] = f2bf_rne(v - bf2f(hi));
        }
    }

    // zero rowAcc (consumed by K2 across the kernel boundary)
    if (bid < 4) rowAcc[bid * 256 + t] = 0.f;
}

// ---------------------------------------------------------------------------
// K2: layer-2 GEMM, both heads, 32(rows)x16(cols) patch, K=256. 512 blocks =
// 32 rt x 16 ct. Wave w: head=w&1, mt=w>>1. Double-buffered staging + reg
// prefetch: 5 barriers total. B (w2) split in-register from fp32 during
// staging. Moment fold: 128 sets, folded after kt loop (no extra barriers).
// ---------------------------------------------------------------------------
__global__ __launch_bounds__(256, 2)
void k2_fused(const unsigned short* __restrict__ hmH, const unsigned short* __restrict__ hmL,
              const unsigned short* __restrict__ hlH, const unsigned short* __restrict__ hlL,
              const float* __restrict__ w2m, const float* __restrict__ w2l,
              const float* __restrict__ b2m, const float* __restrict__ b2l,
              const float* __restrict__ y, const float* __restrict__ z,
              const float* __restrict__ pA1, const float* __restrict__ pB1,
              float* __restrict__ rowAcc) {
    const int bid = blockIdx.x, t = threadIdx.x;
    const int rt = bid >> 4, ct = bid & 15;
    const int rowBase = rt * 32, colBase = ct * 16;
    const int w = t >> 6, lane = t & 63, quad = lane >> 4, mr = lane & 15;
    const int h = w & 1, mt = w >> 1;

    __shared__ __align__(16) unsigned short Ast[2][2][2][32][LSB]; // [buf][head][hl]
    __shared__ __align__(16) unsigned short Bst[2][2][2][16][LSB];
    __shared__ float Cx[2][32][17];
    __shared__ float partA[16][16], partB[16][16];
    __shared__ float mAf[16], mBf[16];

    const unsigned short* Aarr[4] = {hmH, hmL, hlH, hlL};

    // ---- moment partial loads (fold deferred to after the kt loop) ----
    {
        int s = t >> 4, c = t & 15;      // 8 loads per thread (sets 8s..8s+7)
        float a0 = 0.f, b0 = 0.f;
#pragma unroll
        for (int j = 0; j < 8; j++) {
            a0 += pA1[(s * 8 + j) * 256 + colBase + c];
            b0 += pB1[(s * 8 + j) * 256 + colBase + c];
        }
        partA[s][c] = a0;                // written before barrier of kt=0
        partB[s][c] = b0;
    }

    // ---- register prefetch state: A 8x ushort4, B 2x float4 per kt ----
    ushort4 pa[8]; float4 pb[2];
    const int ar_r[2] = { (t + 0) >> 4, (t + 256) >> 4 };   // rows for p=0,1
    const int ar_k = t & 15;
    const int br_r = t >> 4;

#define K2_LOAD(ktv)                                                          \
    {                                                                         \
        int kb = (ktv);                                                       \
        _Pragma("unroll")                                                     \
        for (int ar = 0; ar < 4; ar++) {                                      \
            pa[ar * 2 + 0] = *(const ushort4*)&Aarr[ar][(rowBase + ar_r[0]) * 256 + kb + ar_k * 4]; \
            pa[ar * 2 + 1] = *(const ushort4*)&Aarr[ar][(rowBase + ar_r[1]) * 256 + kb + ar_k * 4]; \
        }                                                                     \
        pb[0] = *(const float4*)&w2m[(colBase + br_r) * 256 + kb + ar_k * 4]; \
        pb[1] = *(const float4*)&w2l[(colBase + br_r) * 256 + kb + ar_k * 4]; \
    }

    K2_LOAD(0);

    f32x4 acc = {0.f, 0.f, 0.f, 0.f};

    for (int kt4 = 0; kt4 < 4; kt4++) {
        int buf = kt4 & 1;
        // write prefetched tile into LDS
#pragma unroll
        for (int ar = 0; ar < 4; ar++) {
            *(ushort4*)&Ast[buf][ar >> 1][ar & 1][ar_r[0]][ar_k * 4] = pa[ar * 2 + 0];
            *(ushort4*)&Ast[buf][ar >> 1][ar & 1][ar_r[1]][ar_k * 4] = pa[ar * 2 + 1];
        }
        {
            ushort4 h4, l4;
            split4(pb[0], h4, l4);
            *(ushort4*)&Bst[buf][0][0][br_r][ar_k * 4] = h4;
            *(ushort4*)&Bst[buf][0][1][br_r][ar_k * 4] = l4;
            split4(pb[1], h4, l4);
            *(ushort4*)&Bst[buf][1][0][br_r][ar_k * 4] = h4;
            *(ushort4*)&Bst[buf][1][1][br_r][ar_k * 4] = l4;
        }
        if (kt4 < 3) K2_LOAD((kt4 + 1) * 64);   // next-tile loads fly under MFMAs
        __syncthreads();                        // single barrier per kt (dbuf)

#pragma unroll
        for (int kk = 0; kk < 64; kk += 32) {
            int ko = kk + quad * 8;
            bf16x8 ah = *(const bf16x8*)&Ast[buf][h][0][mt * 16 + mr][ko];
            bf16x8 al = *(const bf16x8*)&Ast[buf][h][1][mt * 16 + mr][ko];
            bf16x8 bh = *(const bf16x8*)&Bst[buf][h][0][mr][ko];
            bf16x8 bl = *(const bf16x8*)&Bst[buf][h][1][mr][ko];
            acc = __builtin_amdgcn_mfma_f32_16x16x32_bf16(ah, bh, acc, 0, 0, 0);
            acc = __builtin_amdgcn_mfma_f32_16x16x32_bf16(ah, bl, acc, 0, 0, 0);
            acc = __builtin_amdgcn_mfma_f32_16x16x32_bf16(al, bh, acc, 0, 0, 0);
        }
    }
#undef K2_LOAD

    // ---- exchange mu/lv via LDS (C/D: col=lane&15, row=quad*4+reg) ----
    {
        const float* bias = h ? b2l : b2m;
        float bb = bias[colBase + mr];
#pragma unroll
        for (int reg = 0; reg < 4; reg++)
            Cx[h][mt * 16 + quad * 4 + reg][mr] = acc[reg] + bb;
    }
    // moment fold: partA/partB stable since barrier(kt=0); mAf consumed
    // only after the barrier below.
    if (t < 16) {
        float sA = 0.f, sB = 0.f;
#pragma unroll
        for (int s = 0; s < 16; s++) { sA += partA[s][t]; sB += partB[s][t]; }
        mAf[t] = sA * (1.f / 1024.f);
        mBf[t] = sB * (1.f / 1024.f);
    }
    __syncthreads();

    // ---- in-block CLUB epilogue: 32x16 patch; reduce 16 cols -> rowAcc ----
    {
        int col = t & 15, rg = t >> 4;        // rg 0..15, 2 rows each
        int gcol = colBase + col;
        float mA = mAf[col], mB = mBf[col];
#pragma unroll
        for (int rr = 0; rr < 2; rr++) {
            int row = rg * 2 + rr;
            int o = (rowBase + row) * 256 + gcol;
            float m  = Cx[0][row][col];
            float lv = tanhf(Cx[1][row][col]);
            float iv = 0.5f * expf(-lv);      // 1/(2*exp(logvar))
            float yv = y[o];
            float zv = z[o];
            float Mt = mA - 2.f * m * mB + 2.f * m * m;
            float dy = m - yv, dz = m - zv;
            float term = iv * (Mt - dy * dy - dz * dz);
#pragma unroll
            for (int msk = 8; msk; msk >>= 1)
                term += __shfl_xor(term, msk, 16);
            if (col == 0) atomicAdd(&rowAcc[rowBase + row], term);  // no fence
        }
    }
}

// ---------------------------------------------------------------------------
// K3: 1 block. out = mean_i relu(rowAcc[i]).
// ---------------------------------------------------------------------------
__global__ __launch_bounds__(256)
void k3_final(const float* __restrict__ rowAcc, float* __restrict__ out) {
    __shared__ float red[4];
    int t = threadIdx.x, lane = t & 63, wave = t >> 6;
    float v = 0.f;
#pragma unroll
    for (int p = 0; p < 4; p++)
        v += fmaxf(rowAcc[p * 256 + t], 0.f);
#pragma unroll
    for (int msk = 32; msk; msk >>= 1)
        v += __shfl_xor(v, msk, 64);
    if (lane == 0) red[wave] = v;
    __syncthreads();
    if (t == 0)
        out[0] = (red[0] + red[1] + red[2] + red[3]) * (1.f / 1024.f);
}

// ---------------------------------------------------------------------------
extern "C" void kernel_launch(void* const* d_in, const int* in_sizes, int n_in,
                              void* d_out, int out_size, void* d_ws, size_t ws_size,
                              hipStream_t stream) {
    const float* x   = (const float*)d_in[0];
    const float* y   = (const float*)d_in[1];
    const float* zs  = (const float*)d_in[2];
    const float* w1m = (const float*)d_in[3];
    const float* b1m = (const float*)d_in[4];
    const float* w2m = (const float*)d_in[5];
    const float* b2m = (const float*)d_in[6];
    const float* w1l = (const float*)d_in[7];
    const float* b1l = (const float*)d_in[8];
    const float* w2l = (const float*)d_in[9];
    const float* b2l = (const float*)d_in[10];
    float* out = (float*)d_out;

    char* ws = (char*)d_ws;
    float* pA1    = (float*)(ws);                      // 128x256 f32 = 128 KB
    float* pB1    = (float*)(ws + (256u << 10));       // 128 KB
    float* rowAcc = (float*)(ws + (512u << 10));       // 4 KB
    unsigned short* hmH = (unsigned short*)(ws + (1024u << 10));  // 512 KB each
    unsigned short* hmL = (unsigned short*)(ws + (1536u << 10));
    unsigned short* hlH = (unsigned short*)(ws + (2048u << 10));
    unsigned short* hlL = (unsigned short*)(ws + (2560u << 10));

    k1_layer1<<<512, 256, 0, stream>>>(x, w1m, w1l, b1m, b1l,
                                       hmH, hmL, hlH, hlL,
                                       y, zs, pA1, pB1, rowAcc);
    k2_fused<<<512, 256, 0, stream>>>(hmH, hmL, hlH, hlL,
                                      w2m, w2l, b2m, b2l,
                                      y, zs, pA1, pB1, rowAcc);
    k3_final<<<1, 256, 0, stream>>>(rowAcc, out);
}